// Round 1
// baseline (38.401 us; speedup 1.0000x reference)
//
#include <hip/hip_runtime.h>

// Problem constants (from reference)
#define B_IMG 8
#define C_IN  16
#define HH    32
#define WW    32
#define COUT  64
#define H0    36
#define H1    6
#define NB    6
// OH = OW = 16; rows per image = 256

// Sequential bit contraction: out = sum_a sigmoid(table)[a] * prod_i (bit(a,5-i)? g_i : 1-g_i)
// computed as repeated halving: v[r] += (v[r+half]-v[r])*g[i], half = 32>>i.
__device__ __forceinline__ float lut_contract(const float* __restrict__ ws, const float g[NB]) {
    float v[64];
    const float4* wv = (const float4*)ws;  // ws is 16B-aligned (multiple of 64 floats into LDS)
#pragma unroll
    for (int q = 0; q < 16; ++q) {
        float4 w4 = wv[q];
        v[q*4+0] = w4.x; v[q*4+1] = w4.y; v[q*4+2] = w4.z; v[q*4+3] = w4.w;
    }
#pragma unroll
    for (int i = 0; i < NB; ++i) {
        const int half = 32 >> i;
        const float gi = g[i];
#pragma unroll
        for (int r = 0; r < half; ++r)
            v[r] += (v[r+half] - v[r]) * gi;
    }
    return v[0];
}

__global__ __launch_bounds__(256) void lutconv_kernel(
    const float* __restrict__ x,
    const int*   __restrict__ idx0,
    const float* __restrict__ table0,
    const int*   __restrict__ idx1,
    const float* __restrict__ table1,
    const int*   __restrict__ idx2,
    const float* __restrict__ table2,
    float*       __restrict__ out)
{
    __shared__ float w0s[H0*64];
    __shared__ float w1s[H1*64];
    __shared__ float w2s[64];
    __shared__ int   offL[H0*NB];
    __shared__ int   dkhL[H0*NB];
    __shared__ int   dkwL[H0*NB];
    __shared__ int   idx1L[H1*NB];
    __shared__ int   idx2L[NB];
    __shared__ float h0s[H0*256];   // [node][tid] — bank = tid%32, conflict-free
    __shared__ float h1s[H1*256];

    const int tid = threadIdx.x;
    const int t   = blockIdx.x & 63;   // output channel
    const int img = blockIdx.x >> 6;   // image

    // --- stage sigmoid(tables) for channel t ---
    for (int j = tid; j < H0*64; j += 256) {
        float v = table0[t*(H0*64) + j];
        w0s[j] = 1.0f / (1.0f + __expf(-v));
    }
    for (int j = tid; j < H1*64; j += 256) {
        float v = table1[t*(H1*64) + j];
        w1s[j] = 1.0f / (1.0f + __expf(-v));
    }
    if (tid < 64) {
        float v = table2[t*64 + tid];
        w2s[tid] = 1.0f / (1.0f + __expf(-v));
    }
    // --- decode idx0 for channel t: column = c*25 + kh*5 + kw (c slowest) ---
    for (int j = tid; j < H0*NB; j += 256) {
        int id  = idx0[t*(H0*NB) + j];
        int c   = id / 25;
        int rem = id - c*25;
        int kh  = rem / 5;
        int kw  = rem - kh*5;
        offL[j] = c*1024 + (kh-2)*32 + (kw-2);
        dkhL[j] = kh - 2;
        dkwL[j] = kw - 2;
    }
    if (tid < H1*NB) idx1L[tid] = idx1[t*(H1*NB) + tid];
    if (tid < NB)    idx2L[tid] = idx2[t*NB + tid];
    __syncthreads();

    // thread = one output pixel of this image
    const int oh  = tid >> 4;
    const int ow  = tid & 15;
    const int oh2 = oh * 2, ow2 = ow * 2;
    const int base = img*(C_IN*HH*WW) + oh2*WW + ow2;

    // --- layer 0: 36 nodes, gather from x (implicit unfold with padding) ---
    for (int n = 0; n < H0; ++n) {
        float g[NB];
#pragma unroll
        for (int i = 0; i < NB; ++i) {
            const int j  = n*NB + i;
            const int ih = oh2 + dkhL[j];
            const int iw = ow2 + dkwL[j];
            const bool ok = ((unsigned)ih < 32u) && ((unsigned)iw < 32u);
            const float v = x[ok ? (base + offL[j]) : 0];
            g[i] = ok ? v : 0.0f;
        }
        h0s[n*256 + tid] = lut_contract(&w0s[n*64], g);
    }

    // --- layer 1: 6 nodes, gather from own h0 values (same tid → no barrier needed) ---
    for (int n = 0; n < H1; ++n) {
        float g[NB];
#pragma unroll
        for (int i = 0; i < NB; ++i)
            g[i] = h0s[idx1L[n*NB + i]*256 + tid];
        h1s[n*256 + tid] = lut_contract(&w1s[n*64], g);
    }

    // --- layer 2: 1 node ---
    {
        float g[NB];
#pragma unroll
        for (int i = 0; i < NB; ++i)
            g[i] = h1s[idx2L[i]*256 + tid];
        const float h2 = lut_contract(w2s, g);
        // out[img][t][oh][ow]
        out[(img*COUT + t)*256 + tid] = h2;
    }
}

extern "C" void kernel_launch(void* const* d_in, const int* in_sizes, int n_in,
                              void* d_out, int out_size, void* d_ws, size_t ws_size,
                              hipStream_t stream) {
    const float* x      = (const float*)d_in[0];
    const int*   idx0   = (const int*)  d_in[1];
    const float* table0 = (const float*)d_in[2];
    const int*   idx1   = (const int*)  d_in[3];
    const float* table1 = (const float*)d_in[4];
    const int*   idx2   = (const int*)  d_in[5];
    const float* table2 = (const float*)d_in[6];
    float* out = (float*)d_out;

    dim3 grid(COUT * B_IMG);   // 512 blocks: (channel, image)
    dim3 block(256);
    lutconv_kernel<<<grid, block, 0, stream>>>(x, idx0, table0, idx1, table1, idx2, table2, out);
}